// Round 6
// baseline (399.013 us; speedup 1.0000x reference)
//
#include <hip/hip_runtime.h>

#define IH 512
#define IW 512
#define OH 502
#define OW 502
#define KS 11
#define HO 16                 /* output rows per strip */
#define NSTRIP 32             /* 502/16 -> 32 strips (last partly discarded) */
#define NCH 48                /* 16*3 */
#define NBLK (NCH * NSTRIP)   /* 1536 = 6 blocks/CU exactly */
#define NT 256                /* 256 threads * 2 cols = 512 cols */
#define LROW 528              /* padded LDS row (max read idx 523) */
#define C1f 0.0001f
#define C2f 0.0009f

// Gaussian(sigma=1.5, k=11) weights, precomputed in double precision.
__device__ __constant__ float g_w[KS] = {
    0.00102838f, 0.00759876f, 0.03600077f, 0.10936069f, 0.21300554f,
    0.26601173f, 0.21300554f, 0.10936069f, 0.03600077f, 0.00759876f,
    0.00102838f};

// Raw barrier: drain LDS ops (cross-wave visibility) but leave global
// prefetch loads in flight across the barrier (no vmcnt drain).
#define BARRIER() do {                                        \
    asm volatile("s_waitcnt lgkmcnt(0)" ::: "memory");        \
    __builtin_amdgcn_s_barrier();                             \
} while (0)

__global__ __launch_bounds__(NT, 6) void ssim_main(const float* __restrict__ x,
                                                   const float* __restrict__ y,
                                                   double* __restrict__ acc,
                                                   unsigned int* __restrict__ cnt,
                                                   float* __restrict__ out) {
    __shared__ float lds[5][2][LROW];   /* 5 quantities x 2 rows, single buffer */
    __shared__ float red[4];

    const int t = threadIdx.x;            // owns input cols 2t, 2t+1
    const int ch = blockIdx.x / NSTRIP;
    const int strip = blockIdx.x % NSTRIP;
    const int r0 = strip * HO;
    const float* __restrict__ xc = x + (size_t)ch * IH * IW + 2 * t;
    const float* __restrict__ yc = y + (size_t)ch * IH * IW + 2 * t;

    // ---- warmup: ring holds input rows r0 .. r0+11 (static indices) ----
    float2 rx[12], ry[12];
#pragma unroll
    for (int i = 0; i < 12; ++i) {
        const int gr = min(r0 + i, IH - 1);
        rx[i] = *(const float2*)(xc + gr * IW);
        ry[i] = *(const float2*)(yc + gr * IW);
    }
    float2 nx0, ny0, nx1, ny1;
    {
        const int g0 = min(r0 + 12, IH - 1);
        const int g1 = min(r0 + 13, IH - 1);
        nx0 = *(const float2*)(xc + g0 * IW);
        ny0 = *(const float2*)(yc + g0 * IW);
        nx1 = *(const float2*)(xc + g1 * IW);
        ny1 = *(const float2*)(yc + g1 * IW);
    }

    float lsum = 0.f;

    for (int k = 0; k < HO / 2; ++k) {
        // ---- vertical blur, rows 2k (taps rx[0..10]) and 2k+1 (rx[1..11]) ----
#pragma unroll
        for (int rr = 0; rr < 2; ++rr) {
            float s0[2] = {0.f, 0.f}, s1[2] = {0.f, 0.f}, s2[2] = {0.f, 0.f};
            float s3[2] = {0.f, 0.f}, s4[2] = {0.f, 0.f};
#pragma unroll
            for (int tp = 0; tp < KS; ++tp) {
                const float w = g_w[tp];
                const float2 xv = rx[rr + tp];   // static index
                const float2 yv = ry[rr + tp];
                const float wx0 = w * xv.x, wx1 = w * xv.y;
                const float wy0 = w * yv.x, wy1 = w * yv.y;
                s0[0] += wx0;  s0[1] += wx1;
                s1[0] += wy0;  s1[1] += wy1;
                s2[0] = fmaf(wx0, xv.x, s2[0]);  s2[1] = fmaf(wx1, xv.y, s2[1]);
                s3[0] = fmaf(wy0, yv.x, s3[0]);  s3[1] = fmaf(wy1, yv.y, s3[1]);
                s4[0] = fmaf(wx0, yv.x, s4[0]);  s4[1] = fmaf(wx1, yv.y, s4[1]);
            }
            *(float2*)&lds[0][rr][2 * t] = make_float2(s0[0], s0[1]);
            *(float2*)&lds[1][rr][2 * t] = make_float2(s1[0], s1[1]);
            *(float2*)&lds[2][rr][2 * t] = make_float2(s2[0], s2[1]);
            *(float2*)&lds[3][rr][2 * t] = make_float2(s3[0], s3[1]);
            *(float2*)&lds[4][rr][2 * t] = make_float2(s4[0], s4[1]);
        }
        BARRIER();   // writes visible; prefetch stays in flight

        // ---- horizontal blur + ssim: 256 tasks = 2 rows x 128 4-col chunks ----
        {
            const int rr = t >> 7;            // wave-uniform
            const int c4 = (t & 127) * 4;
            const int orow = r0 + 2 * k + rr;
            float m[5][4];
#pragma unroll
            for (int q = 0; q < 5; ++q) {
                float f[16];
#pragma unroll
                for (int a = 0; a < 4; ++a)
                    *(float4*)&f[4 * a] = *(const float4*)&lds[q][rr][c4 + 4 * a];
#pragma unroll
                for (int cc = 0; cc < 4; ++cc) {
                    float s = 0.f;
#pragma unroll
                    for (int tp = 0; tp < KS; ++tp) s = fmaf(g_w[tp], f[cc + tp], s);
                    m[q][cc] = s;
                }
            }
            if (orow < OH) {
#pragma unroll
                for (int cc = 0; cc < 4; ++cc) {
                    const int gc = c4 + cc;
                    if (gc < OW) {
                        const float mux2 = m[0][cc] * m[0][cc];
                        const float muy2 = m[1][cc] * m[1][cc];
                        const float muxy = m[0][cc] * m[1][cc];
                        const float vx = m[2][cc] - mux2;
                        const float vy = m[3][cc] - muy2;
                        const float cxy = m[4][cc] - muxy;
                        const float num = (2.f * muxy + C1f) * (2.f * cxy + C2f);
                        const float den = (mux2 + muy2 + C1f) * (vx + vy + C2f);
                        float r = __builtin_amdgcn_rcpf(den);
                        r = r * fmaf(-den, r, 2.0f);   // Newton step
                        lsum = fmaf(num, r, lsum);
                    }
                }
            }
        }

        // ---- shift ring by 2 (static -> VGPRs), commit prefetch ----
#pragma unroll
        for (int i = 0; i < 10; ++i) { rx[i] = rx[i + 2]; ry[i] = ry[i + 2]; }
        rx[10] = nx0; ry[10] = ny0;
        rx[11] = nx1; ry[11] = ny1;

        // ---- issue next 2-row prefetch (consumed at next iter's shift) ----
        {
            const int g0 = min(r0 + 2 * k + 14, IH - 1);
            const int g1 = min(r0 + 2 * k + 15, IH - 1);
            nx0 = *(const float2*)(xc + g0 * IW);
            ny0 = *(const float2*)(yc + g0 * IW);
            nx1 = *(const float2*)(xc + g1 * IW);
            ny1 = *(const float2*)(yc + g1 * IW);
        }
        BARRIER();   // reads of this iter done before next iter's writes (WAR)
    }

    // ---- block reduce (4 waves of 64) + last-block finalize ----
#pragma unroll
    for (int off = 32; off > 0; off >>= 1) lsum += __shfl_down(lsum, off, 64);
    const int wave = t >> 6, lane = t & 63;
    if (lane == 0) red[wave] = lsum;
    __syncthreads();
    if (t == 0) {
        const float bs = (red[0] + red[1]) + (red[2] + red[3]);
        atomicAdd(acc, (double)bs);
        __threadfence();
        const unsigned int prev = atomicAdd(cnt, 1u);
        if (prev == (unsigned int)(NBLK - 1)) {
            const double total = atomicAdd(acc, 0.0);  // coherent read
            out[0] = (float)(1.0 - total / 12096192.0);  // 48*502*502
        }
    }
}

extern "C" void kernel_launch(void* const* d_in, const int* in_sizes, int n_in,
                              void* d_out, int out_size, void* d_ws, size_t ws_size,
                              hipStream_t stream) {
    const float* x = (const float*)d_in[0];
    const float* y = (const float*)d_in[1];
    float* out = (float*)d_out;
    double* acc = (double*)d_ws;
    unsigned int* cnt = (unsigned int*)((char*)d_ws + 8);

    hipMemsetAsync(d_ws, 0, 16, stream);
    ssim_main<<<NBLK, NT, 0, stream>>>(x, y, acc, cnt, out);
}

// Round 7
// 287.566 us; speedup vs baseline: 1.3876x; 1.3876x over previous
//
#include <hip/hip_runtime.h>

#define IH 512
#define IW 512
#define OH 502
#define OW 502
#define KS 11
#define HO 16                 /* output rows per strip */
#define NSTRIP 32             /* 32 strips of 16 rows */
#define NCH 48                /* 16*3 */
#define NBLK (NCH * NSTRIP)   /* 1536 */
#define NT 128                /* 128 threads * 4 cols = 512 cols */
#define LROW 524              /* LDS row; max read idx 523 */
#define C1f 0.0001f
#define C2f 0.0009f

// Gaussian(sigma=1.5, k=11) weights, precomputed in double precision.
__device__ __constant__ float g_w[KS] = {
    0.00102838f, 0.00759876f, 0.03600077f, 0.10936069f, 0.21300554f,
    0.26601173f, 0.21300554f, 0.10936069f, 0.03600077f, 0.00759876f,
    0.00102838f};

// Raw barrier: drain LDS ops (cross-wave visibility) but leave global
// prefetch loads in flight (no vmcnt drain, unlike __syncthreads).
#define BARRIER() do {                                        \
    asm volatile("s_waitcnt lgkmcnt(0)" ::: "memory");        \
    __builtin_amdgcn_s_barrier();                             \
} while (0)

__global__ __launch_bounds__(NT, 4) void ssim_main(const float* __restrict__ x,
                                                   const float* __restrict__ y,
                                                   double* __restrict__ acc,
                                                   unsigned int* __restrict__ cnt,
                                                   float* __restrict__ out) {
    __shared__ float lds[5][LROW];   /* single buffer; WAR guarded by barrier2 */
    __shared__ float red[2];

    const int t = threadIdx.x;            // owns cols 4t..4t+3
    const int ch = blockIdx.x / NSTRIP;
    const int strip = blockIdx.x % NSTRIP;
    const int r0 = strip * HO;
    const float* __restrict__ xc = x + (size_t)ch * IH * IW + 4 * t;
    const float* __restrict__ yc = y + (size_t)ch * IH * IW + 4 * t;

    // ---- warmup: ring holds input rows r0 .. r0+10 (static indices) ----
    float4 rx[KS], ry[KS];
#pragma unroll
    for (int i = 0; i < KS; ++i) {
        const int gr = min(r0 + i, IH - 1);
        rx[i] = *(const float4*)(xc + gr * IW);
        ry[i] = *(const float4*)(yc + gr * IW);
    }
    // prefetch row r0+11 (committed at end of iter 0)
    float4 nx, ny;
    {
        const int gr = min(r0 + KS, IH - 1);
        nx = *(const float4*)(xc + gr * IW);
        ny = *(const float4*)(yc + gr * IW);
    }

    float lsum = 0.f;

    for (int k = 0; k < HO; ++k) {
        // ---- vertical blur of 5 quantities from the register ring ----
        float s0[4] = {0.f, 0.f, 0.f, 0.f};
        float s1[4] = {0.f, 0.f, 0.f, 0.f};
        float s2[4] = {0.f, 0.f, 0.f, 0.f};
        float s3[4] = {0.f, 0.f, 0.f, 0.f};
        float s4[4] = {0.f, 0.f, 0.f, 0.f};
#pragma unroll
        for (int tp = 0; tp < KS; ++tp) {
            const float w = g_w[tp];
            const float xa[4] = {rx[tp].x, rx[tp].y, rx[tp].z, rx[tp].w};
            const float ya[4] = {ry[tp].x, ry[tp].y, ry[tp].z, ry[tp].w};
#pragma unroll
            for (int j = 0; j < 4; ++j) {
                const float wx = w * xa[j];
                const float wy = w * ya[j];
                s0[j] += wx;
                s1[j] += wy;
                s2[j] = fmaf(wx, xa[j], s2[j]);
                s3[j] = fmaf(wy, ya[j], s3[j]);
                s4[j] = fmaf(wx, ya[j], s4[j]);
            }
        }

        *(float4*)&lds[0][4 * t] = make_float4(s0[0], s0[1], s0[2], s0[3]);
        *(float4*)&lds[1][4 * t] = make_float4(s1[0], s1[1], s1[2], s1[3]);
        *(float4*)&lds[2][4 * t] = make_float4(s2[0], s2[1], s2[2], s2[3]);
        *(float4*)&lds[3][4 * t] = make_float4(s3[0], s3[1], s3[2], s3[3]);
        *(float4*)&lds[4][4 * t] = make_float4(s4[0], s4[1], s4[2], s4[3]);
        BARRIER();   // barrier1: writes visible; prefetch stays in flight

        // ---- horizontal blur + ssim for output row r0+k, cols 4t..4t+3 ----
        const int orow = r0 + k;
        float m[5][4];
#pragma unroll
        for (int q = 0; q < 5; ++q) {
            float f[16];
#pragma unroll
            for (int a = 0; a < 4; ++a)
                *(float4*)&f[4 * a] = *(const float4*)&lds[q][4 * t + 4 * a];
#pragma unroll
            for (int cc = 0; cc < 4; ++cc) {
                float s = 0.f;
#pragma unroll
                for (int tp = 0; tp < KS; ++tp) s = fmaf(g_w[tp], f[cc + tp], s);
                m[q][cc] = s;
            }
        }
        if (orow < OH) {
#pragma unroll
            for (int cc = 0; cc < 4; ++cc) {
                const int gc = 4 * t + cc;
                if (gc < OW) {
                    const float mux2 = m[0][cc] * m[0][cc];
                    const float muy2 = m[1][cc] * m[1][cc];
                    const float muxy = m[0][cc] * m[1][cc];
                    const float vx = m[2][cc] - mux2;
                    const float vy = m[3][cc] - muy2;
                    const float cxy = m[4][cc] - muxy;
                    const float num = (2.f * muxy + C1f) * (2.f * cxy + C2f);
                    const float den = (mux2 + muy2 + C1f) * (vx + vy + C2f);
                    float r = __builtin_amdgcn_rcpf(den);
                    r = r * fmaf(-den, r, 2.0f);   // Newton step
                    lsum = fmaf(num, r, lsum);
                }
            }
        }
        BARRIER();   // barrier2: all hblur reads done before next iter's writes

        // ---- shift ring (static -> VGPRs), commit prefetch (arrived ~1 iter ago) ----
#pragma unroll
        for (int i = 0; i < KS - 1; ++i) { rx[i] = rx[i + 1]; ry[i] = ry[i + 1]; }
        rx[KS - 1] = nx;
        ry[KS - 1] = ny;

        // ---- issue next prefetch (consumed at end of next iter) ----
        {
            const int gr = min(r0 + k + KS + 1, IH - 1);
            nx = *(const float4*)(xc + gr * IW);
            ny = *(const float4*)(yc + gr * IW);
        }
    }

    // ---- block reduce (2 waves of 64) + last-block finalize ----
#pragma unroll
    for (int off = 32; off > 0; off >>= 1) lsum += __shfl_down(lsum, off, 64);
    const int wave = t >> 6, lane = t & 63;
    if (lane == 0) red[wave] = lsum;
    __syncthreads();
    if (t == 0) {
        const float bs = red[0] + red[1];
        atomicAdd(acc, (double)bs);
        __threadfence();
        const unsigned int prev = atomicAdd(cnt, 1u);
        if (prev == (unsigned int)(NBLK - 1)) {
            const double total = atomicAdd(acc, 0.0);  // coherent read
            out[0] = (float)(1.0 - total / 12096192.0);  // 48*502*502
        }
    }
}

extern "C" void kernel_launch(void* const* d_in, const int* in_sizes, int n_in,
                              void* d_out, int out_size, void* d_ws, size_t ws_size,
                              hipStream_t stream) {
    const float* x = (const float*)d_in[0];
    const float* y = (const float*)d_in[1];
    float* out = (float*)d_out;
    double* acc = (double*)d_ws;
    unsigned int* cnt = (unsigned int*)((char*)d_ws + 8);

    hipMemsetAsync(d_ws, 0, 16, stream);
    ssim_main<<<NBLK, NT, 0, stream>>>(x, y, acc, cnt, out);
}

// Round 8
// 90.791 us; speedup vs baseline: 4.3948x; 3.1673x over previous
//
#include <hip/hip_runtime.h>

#define IH 512
#define IW 512
#define OH 502
#define OW 502
#define KS 11
#define HO 16                 /* output rows per strip */
#define NSTRIP 32             /* 32 strips of 16 rows */
#define NCH 48                /* 16*3 */
#define NBLK (NCH * NSTRIP)   /* 1536 = 6 blocks/CU */
#define NT 256                /* 256 threads * 2 cols = 512 cols */
#define LROW 528              /* padded LDS row (max read idx 523) */
#define C1f 0.0001f
#define C2f 0.0009f

// Gaussian(sigma=1.5, k=11) weights, precomputed in double precision.
__device__ __constant__ float g_w[KS] = {
    0.00102838f, 0.00759876f, 0.03600077f, 0.10936069f, 0.21300554f,
    0.26601173f, 0.21300554f, 0.10936069f, 0.03600077f, 0.00759876f,
    0.00102838f};

// Raw barrier: drain LDS ops (cross-wave visibility) but leave global
// prefetch loads in flight across the barrier (no vmcnt drain).
#define BARRIER() do {                                        \
    asm volatile("s_waitcnt lgkmcnt(0)" ::: "memory");        \
    __builtin_amdgcn_s_barrier();                             \
} while (0)

// launch_bounds 2nd arg: empirically min WORKGROUPS/EU on hipcc
// ((128,3)->84, (128,4)->64, (256,6)->40 regs). (256,1) -> 4 waves/EU
// -> 128-reg cap; this kernel needs ~100 -> no spill.
__global__ __launch_bounds__(NT, 1) void ssim_main(const float* __restrict__ x,
                                                   const float* __restrict__ y,
                                                   double* __restrict__ acc,
                                                   unsigned int* __restrict__ cnt,
                                                   float* __restrict__ out) {
    __shared__ float lds[5][2][LROW];   /* 5 quantities x 2 rows, single buffer */
    __shared__ float red[4];

    const int t = threadIdx.x;            // owns input cols 2t, 2t+1
    const int ch = blockIdx.x / NSTRIP;
    const int strip = blockIdx.x % NSTRIP;
    const int r0 = strip * HO;
    const float* __restrict__ xc = x + (size_t)ch * IH * IW + 2 * t;
    const float* __restrict__ yc = y + (size_t)ch * IH * IW + 2 * t;

    // ---- warmup: ring holds input rows r0 .. r0+11 (static indices) ----
    float2 rx[12], ry[12];
#pragma unroll
    for (int i = 0; i < 12; ++i) {
        const int gr = min(r0 + i, IH - 1);
        rx[i] = *(const float2*)(xc + gr * IW);
        ry[i] = *(const float2*)(yc + gr * IW);
    }
    float2 nx0, ny0, nx1, ny1;
    {
        const int g0 = min(r0 + 12, IH - 1);
        const int g1 = min(r0 + 13, IH - 1);
        nx0 = *(const float2*)(xc + g0 * IW);
        ny0 = *(const float2*)(yc + g0 * IW);
        nx1 = *(const float2*)(xc + g1 * IW);
        ny1 = *(const float2*)(yc + g1 * IW);
    }

    float lsum = 0.f;

    for (int k = 0; k < HO / 2; ++k) {
        // ---- vertical blur, rows 2k (taps rx[0..10]) and 2k+1 (rx[1..11]) ----
#pragma unroll
        for (int rr = 0; rr < 2; ++rr) {
            float s0[2] = {0.f, 0.f}, s1[2] = {0.f, 0.f}, s2[2] = {0.f, 0.f};
            float s3[2] = {0.f, 0.f}, s4[2] = {0.f, 0.f};
#pragma unroll
            for (int tp = 0; tp < KS; ++tp) {
                const float w = g_w[tp];
                const float2 xv = rx[rr + tp];   // static index
                const float2 yv = ry[rr + tp];
                const float wx0 = w * xv.x, wx1 = w * xv.y;
                const float wy0 = w * yv.x, wy1 = w * yv.y;
                s0[0] += wx0;  s0[1] += wx1;
                s1[0] += wy0;  s1[1] += wy1;
                s2[0] = fmaf(wx0, xv.x, s2[0]);  s2[1] = fmaf(wx1, xv.y, s2[1]);
                s3[0] = fmaf(wy0, yv.x, s3[0]);  s3[1] = fmaf(wy1, yv.y, s3[1]);
                s4[0] = fmaf(wx0, yv.x, s4[0]);  s4[1] = fmaf(wx1, yv.y, s4[1]);
            }
            *(float2*)&lds[0][rr][2 * t] = make_float2(s0[0], s0[1]);
            *(float2*)&lds[1][rr][2 * t] = make_float2(s1[0], s1[1]);
            *(float2*)&lds[2][rr][2 * t] = make_float2(s2[0], s2[1]);
            *(float2*)&lds[3][rr][2 * t] = make_float2(s3[0], s3[1]);
            *(float2*)&lds[4][rr][2 * t] = make_float2(s4[0], s4[1]);
        }
        BARRIER();   // writes visible; prefetch stays in flight

        // ---- horizontal blur + ssim: 256 tasks = 2 rows x 128 4-col chunks ----
        {
            const int rr = t >> 7;            // wave-uniform
            const int c4 = (t & 127) * 4;
            const int orow = r0 + 2 * k + rr;
            float m[5][4];
#pragma unroll
            for (int q = 0; q < 5; ++q) {
                float f[16];
#pragma unroll
                for (int a = 0; a < 4; ++a)
                    *(float4*)&f[4 * a] = *(const float4*)&lds[q][rr][c4 + 4 * a];
#pragma unroll
                for (int cc = 0; cc < 4; ++cc) {
                    float s = 0.f;
#pragma unroll
                    for (int tp = 0; tp < KS; ++tp) s = fmaf(g_w[tp], f[cc + tp], s);
                    m[q][cc] = s;
                }
            }
            if (orow < OH) {
#pragma unroll
                for (int cc = 0; cc < 4; ++cc) {
                    const int gc = c4 + cc;
                    if (gc < OW) {
                        const float mux2 = m[0][cc] * m[0][cc];
                        const float muy2 = m[1][cc] * m[1][cc];
                        const float muxy = m[0][cc] * m[1][cc];
                        const float vx = m[2][cc] - mux2;
                        const float vy = m[3][cc] - muy2;
                        const float cxy = m[4][cc] - muxy;
                        const float num = (2.f * muxy + C1f) * (2.f * cxy + C2f);
                        const float den = (mux2 + muy2 + C1f) * (vx + vy + C2f);
                        float r = __builtin_amdgcn_rcpf(den);
                        r = r * fmaf(-den, r, 2.0f);   // Newton step
                        lsum = fmaf(num, r, lsum);
                    }
                }
            }
        }

        // ---- shift ring by 2 (static -> VGPRs), commit prefetch ----
#pragma unroll
        for (int i = 0; i < 10; ++i) { rx[i] = rx[i + 2]; ry[i] = ry[i + 2]; }
        rx[10] = nx0; ry[10] = ny0;
        rx[11] = nx1; ry[11] = ny1;

        // ---- issue next 2-row prefetch (consumed at next iter's shift) ----
        {
            const int g0 = min(r0 + 2 * k + 14, IH - 1);
            const int g1 = min(r0 + 2 * k + 15, IH - 1);
            nx0 = *(const float2*)(xc + g0 * IW);
            ny0 = *(const float2*)(yc + g0 * IW);
            nx1 = *(const float2*)(xc + g1 * IW);
            ny1 = *(const float2*)(yc + g1 * IW);
        }
        BARRIER();   // reads of this iter done before next iter's writes (WAR)
    }

    // ---- block reduce (4 waves of 64) + last-block finalize ----
#pragma unroll
    for (int off = 32; off > 0; off >>= 1) lsum += __shfl_down(lsum, off, 64);
    const int wave = t >> 6, lane = t & 63;
    if (lane == 0) red[wave] = lsum;
    __syncthreads();
    if (t == 0) {
        const float bs = (red[0] + red[1]) + (red[2] + red[3]);
        atomicAdd(acc, (double)bs);
        __threadfence();
        const unsigned int prev = atomicAdd(cnt, 1u);
        if (prev == (unsigned int)(NBLK - 1)) {
            const double total = atomicAdd(acc, 0.0);  // coherent read
            out[0] = (float)(1.0 - total / 12096192.0);  // 48*502*502
        }
    }
}

extern "C" void kernel_launch(void* const* d_in, const int* in_sizes, int n_in,
                              void* d_out, int out_size, void* d_ws, size_t ws_size,
                              hipStream_t stream) {
    const float* x = (const float*)d_in[0];
    const float* y = (const float*)d_in[1];
    float* out = (float*)d_out;
    double* acc = (double*)d_ws;
    unsigned int* cnt = (unsigned int*)((char*)d_ws + 8);

    hipMemsetAsync(d_ws, 0, 16, stream);
    ssim_main<<<NBLK, NT, 0, stream>>>(x, y, acc, cnt, out);
}

// Round 9
// 85.264 us; speedup vs baseline: 4.6797x; 1.0648x over previous
//
#include <hip/hip_runtime.h>

#define IH 512
#define IW 512
#define OH 502
#define OW 502
#define KS 11
#define HO 16                 /* output rows per strip */
#define NSTRIP 32             /* 32 strips of 16 rows */
#define NCH 48                /* 16*3 */
#define NBLK (NCH * NSTRIP)   /* 1536 = 6 blocks/CU, single fill at 8 waves/SIMD */
#define NT 256                /* 256 threads * 2 cols = 512 cols */
#define LROW 528              /* padded LDS row (max read idx 523) */
#define C1f 0.0001f
#define C2f 0.0009f

// Gaussian(sigma=1.5, k=11) weights, precomputed in double precision.
__device__ __constant__ float g_w[KS] = {
    0.00102838f, 0.00759876f, 0.03600077f, 0.10936069f, 0.21300554f,
    0.26601173f, 0.21300554f, 0.10936069f, 0.03600077f, 0.00759876f,
    0.00102838f};

// Raw barrier: drain LDS ops (cross-wave visibility) but leave global
// prefetch loads in flight across the barrier (no vmcnt drain).
#define BARRIER() do {                                        \
    asm volatile("s_waitcnt lgkmcnt(0)" ::: "memory");        \
    __builtin_amdgcn_s_barrier();                             \
} while (0)

// (256,2) => 8 waves/EU => 64-VGPR cap => 8 waves/SIMD occupancy step.
// 11-row ring (44 regs) instead of 12 keeps natural usage at ~64: row 2k+1's
// last tap reads the prefetch reg nx0 directly.
__global__ __launch_bounds__(NT, 2) void ssim_main(const float* __restrict__ x,
                                                   const float* __restrict__ y,
                                                   double* __restrict__ acc,
                                                   unsigned int* __restrict__ cnt,
                                                   float* __restrict__ out) {
    __shared__ float lds[5][2][LROW];   /* 5 quantities x 2 rows */
    __shared__ float red[4];

    const int t = threadIdx.x;            // owns input cols 2t, 2t+1
    const int ch = blockIdx.x / NSTRIP;
    const int strip = blockIdx.x % NSTRIP;
    const int r0 = strip * HO;
    const float* __restrict__ xc = x + (size_t)ch * IH * IW + 2 * t;
    const float* __restrict__ yc = y + (size_t)ch * IH * IW + 2 * t;

    // ---- warmup: ring holds input rows r0 .. r0+10 (static indices) ----
    float2 rx[KS], ry[KS];
#pragma unroll
    for (int i = 0; i < KS; ++i) {
        const int gr = min(r0 + i, IH - 1);
        rx[i] = *(const float2*)(xc + gr * IW);
        ry[i] = *(const float2*)(yc + gr * IW);
    }
    float2 nx0, ny0, nx1, ny1;
    {
        const int g0 = min(r0 + 11, IH - 1);
        const int g1 = min(r0 + 12, IH - 1);
        nx0 = *(const float2*)(xc + g0 * IW);
        ny0 = *(const float2*)(yc + g0 * IW);
        nx1 = *(const float2*)(xc + g1 * IW);
        ny1 = *(const float2*)(yc + g1 * IW);
    }

    float lsum = 0.f;

    for (int k = 0; k < HO / 2; ++k) {
        // ---- vblur row A (2k): taps ring[0..10] ----
        {
            float s0[2] = {0.f, 0.f}, s1[2] = {0.f, 0.f}, s2[2] = {0.f, 0.f};
            float s3[2] = {0.f, 0.f}, s4[2] = {0.f, 0.f};
#pragma unroll
            for (int tp = 0; tp < KS; ++tp) {
                const float w = g_w[tp];
                const float2 xv = rx[tp];
                const float2 yv = ry[tp];
                const float wx0 = w * xv.x, wx1 = w * xv.y;
                const float wy0 = w * yv.x, wy1 = w * yv.y;
                s0[0] += wx0;  s0[1] += wx1;
                s1[0] += wy0;  s1[1] += wy1;
                s2[0] = fmaf(wx0, xv.x, s2[0]);  s2[1] = fmaf(wx1, xv.y, s2[1]);
                s3[0] = fmaf(wy0, yv.x, s3[0]);  s3[1] = fmaf(wy1, yv.y, s3[1]);
                s4[0] = fmaf(wx0, yv.x, s4[0]);  s4[1] = fmaf(wx1, yv.y, s4[1]);
            }
            *(float2*)&lds[0][0][2 * t] = make_float2(s0[0], s0[1]);
            *(float2*)&lds[1][0][2 * t] = make_float2(s1[0], s1[1]);
            *(float2*)&lds[2][0][2 * t] = make_float2(s2[0], s2[1]);
            *(float2*)&lds[3][0][2 * t] = make_float2(s3[0], s3[1]);
            *(float2*)&lds[4][0][2 * t] = make_float2(s4[0], s4[1]);
        }
        // ---- vblur row B (2k+1): taps ring[1..10] + nx0/ny0 as tap 10 ----
        {
            float s0[2] = {0.f, 0.f}, s1[2] = {0.f, 0.f}, s2[2] = {0.f, 0.f};
            float s3[2] = {0.f, 0.f}, s4[2] = {0.f, 0.f};
#pragma unroll
            for (int tp = 0; tp < KS; ++tp) {
                const float w = g_w[tp];
                const float2 xv = (tp < KS - 1) ? rx[tp + 1] : nx0;  // static
                const float2 yv = (tp < KS - 1) ? ry[tp + 1] : ny0;
                const float wx0 = w * xv.x, wx1 = w * xv.y;
                const float wy0 = w * yv.x, wy1 = w * yv.y;
                s0[0] += wx0;  s0[1] += wx1;
                s1[0] += wy0;  s1[1] += wy1;
                s2[0] = fmaf(wx0, xv.x, s2[0]);  s2[1] = fmaf(wx1, xv.y, s2[1]);
                s3[0] = fmaf(wy0, yv.x, s3[0]);  s3[1] = fmaf(wy1, yv.y, s3[1]);
                s4[0] = fmaf(wx0, yv.x, s4[0]);  s4[1] = fmaf(wx1, yv.y, s4[1]);
            }
            *(float2*)&lds[0][1][2 * t] = make_float2(s0[0], s0[1]);
            *(float2*)&lds[1][1][2 * t] = make_float2(s1[0], s1[1]);
            *(float2*)&lds[2][1][2 * t] = make_float2(s2[0], s2[1]);
            *(float2*)&lds[3][1][2 * t] = make_float2(s3[0], s3[1]);
            *(float2*)&lds[4][1][2 * t] = make_float2(s4[0], s4[1]);
        }
        BARRIER();   // barrier1: LDS writes visible; prefetch stays in flight

        // ---- shift ring by 2, commit prefetch, issue next prefetch NOW so it
        // flies under hblur + barrier2 + next vblur-A (~1000+ cycles) ----
#pragma unroll
        for (int i = 0; i < KS - 2; ++i) { rx[i] = rx[i + 2]; ry[i] = ry[i + 2]; }
        rx[KS - 2] = nx0; ry[KS - 2] = ny0;
        rx[KS - 1] = nx1; ry[KS - 1] = ny1;
        {
            const int g0 = min(r0 + 2 * k + 13, IH - 1);
            const int g1 = min(r0 + 2 * k + 14, IH - 1);
            nx0 = *(const float2*)(xc + g0 * IW);
            ny0 = *(const float2*)(yc + g0 * IW);
            nx1 = *(const float2*)(xc + g1 * IW);
            ny1 = *(const float2*)(yc + g1 * IW);
        }

        // ---- hblur + ssim: 256 tasks = 2 rows x 128 4-col chunks ----
        {
            const int rr = t >> 7;            // wave-uniform
            const int c4 = (t & 127) * 4;
            const int orow = r0 + 2 * k + rr;
            float m[5][4];
#pragma unroll
            for (int q = 0; q < 5; ++q) {
                float f[16];
#pragma unroll
                for (int a = 0; a < 4; ++a)
                    *(float4*)&f[4 * a] = *(const float4*)&lds[q][rr][c4 + 4 * a];
#pragma unroll
                for (int cc = 0; cc < 4; ++cc) {
                    float s = 0.f;
#pragma unroll
                    for (int tp = 0; tp < KS; ++tp) s = fmaf(g_w[tp], f[cc + tp], s);
                    m[q][cc] = s;
                }
            }
            if (orow < OH) {
#pragma unroll
                for (int cc = 0; cc < 4; ++cc) {
                    const int gc = c4 + cc;
                    if (gc < OW) {
                        const float mux2 = m[0][cc] * m[0][cc];
                        const float muy2 = m[1][cc] * m[1][cc];
                        const float muxy = m[0][cc] * m[1][cc];
                        const float vx = m[2][cc] - mux2;
                        const float vy = m[3][cc] - muy2;
                        const float cxy = m[4][cc] - muxy;
                        const float num = (2.f * muxy + C1f) * (2.f * cxy + C2f);
                        const float den = (mux2 + muy2 + C1f) * (vx + vy + C2f);
                        float r = __builtin_amdgcn_rcpf(den);
                        r = r * fmaf(-den, r, 2.0f);   // Newton step
                        lsum = fmaf(num, r, lsum);
                    }
                }
            }
        }
        BARRIER();   // barrier2: hblur reads done before next iter's writes (WAR)
    }

    // ---- block reduce (4 waves of 64) + last-block finalize ----
#pragma unroll
    for (int off = 32; off > 0; off >>= 1) lsum += __shfl_down(lsum, off, 64);
    const int wave = t >> 6, lane = t & 63;
    if (lane == 0) red[wave] = lsum;
    __syncthreads();
    if (t == 0) {
        const float bs = (red[0] + red[1]) + (red[2] + red[3]);
        atomicAdd(acc, (double)bs);
        __threadfence();
        const unsigned int prev = atomicAdd(cnt, 1u);
        if (prev == (unsigned int)(NBLK - 1)) {
            const double total = atomicAdd(acc, 0.0);  // coherent read
            out[0] = (float)(1.0 - total / 12096192.0);  // 48*502*502
        }
    }
}

extern "C" void kernel_launch(void* const* d_in, const int* in_sizes, int n_in,
                              void* d_out, int out_size, void* d_ws, size_t ws_size,
                              hipStream_t stream) {
    const float* x = (const float*)d_in[0];
    const float* y = (const float*)d_in[1];
    float* out = (float*)d_out;
    double* acc = (double*)d_ws;
    unsigned int* cnt = (unsigned int*)((char*)d_ws + 8);

    hipMemsetAsync(d_ws, 0, 16, stream);
    ssim_main<<<NBLK, NT, 0, stream>>>(x, y, acc, cnt, out);
}